// Round 23
// baseline (301.559 us; speedup 1.0000x reference)
//
#include <hip/hip_runtime.h>
#include <math.h>

#define NS   4096   // L = 64*64
#define KCH  576    // 64 ch * 3 * 3
#define CH   64
#define HF   128    // full res
#define HD   64     // downsampled res
#define PLANE (NS*KCH)   // elements per fp16 plane
#define IMG  (CH*HF*HF)

typedef __attribute__((ext_vector_type(8))) _Float16 half8;
typedef __attribute__((ext_vector_type(4))) float f32x4;

__device__ __forceinline__ int Tsw(int r){ return ((r & 63) << 6) | (r >> 6); }

typedef __attribute__((address_space(1))) unsigned int gu32;
typedef __attribute__((address_space(3))) unsigned int lu32;
__device__ __forceinline__ void gload16(const void* g, void* l){
  __builtin_amdgcn_global_load_lds((const gu32*)g, (lu32*)l, 16, 0, 0);
}

// ---- mm mask vector (batch 0 of mask only, per reference) ----
__global__ void k_mm(const float* __restrict__ mask, float* __restrict__ mm){
  int n = blockIdx.x * blockDim.x + threadIdx.x;
  if(n >= NS) return;
  float sum = 0.f;
  #pragma unroll
  for(int r9 = 0; r9 < 9; ++r9){
    int idx = n * 9 + r9;
    int p   = idx >> 12;
    int rem = idx & 4095;
    int y = rem >> 6, x = rem & 63;
    int ki = p / 3, kj = p % 3;
    int Y = ki + y - 1, X = kj + x - 1;
    float v = 0.f;
    if(Y >= 0 && Y < HD && X >= 0 && X < HD)
      v = mask[(2*Y) * HF + 2*X];
    sum += v;
  }
  mm[n] = ((sum / 9.0f) == 0.0f) ? 1.0f : 0.0f;
}

// ---- W planes (n-major, scaled by 1e4/1024) and X planes (s-major, scaled by
// 1024), fp16x2. Vectorized: each thread produces 8 consecutive k of one row
// (per-element decode unchanged), short8 stores. Batched: samp = idx/(PLANE/4). ----
__global__ void k_WX(const float* __restrict__ f, const float* __restrict__ b,
                     _Float16* __restrict__ Wp, _Float16* __restrict__ Xp){
  int idx = blockIdx.x * 256 + threadIdx.x;
  int samp = idx / (PLANE/4);
  int ew8  = idx - samp * (PLANE/4);
  const float* fp = f + (size_t)samp * IMG;
  const float* bp = b + (size_t)samp * IMG;
  _Float16* Wps = Wp + (size_t)samp * (2*PLANE);
  _Float16* Xps = Xp + (size_t)samp * (2*PLANE);
  const bool isW = (ew8 < PLANE/8);
  int r8 = isW ? ew8 : ew8 - PLANE/8;
  int n = r8 / 72, j = r8 - n * 72;      // row n, k base 8j (KCH=576=72*8)
  int kb = j << 3;
  half8 h0v, h1v;
  #pragma unroll
  for(int i = 0; i < 8; ++i){
    int k = kb + i;
    float v = 0.f;
    if(isW){
      int c2 = k / 9, r9 = k - c2 * 9;
      int t = n * 9 + r9;               // the scrambling: 64 not divisible by 9
      int y = t & 63, ch = (t >> 6) & 63, p = t >> 12;
      int ki = p / 3, kj = p - ki * 3;
      int Y = ki + y - 1, X = kj + c2 - 1;
      if((unsigned)Y < 64u && (unsigned)X < 64u)
        v = bp[ch * (HF*HF) + (Y << 8) + (X << 1)];
      v *= 9.765625f;                   // 1e4 / 1024, exact
    } else {
      int c2 = k / 9, r9 = k - c2 * 9, a = r9 / 3, bb2 = r9 - a * 3;
      int si = n >> 6, sj = n & 63;
      int Y = si + a - 1, Xc = sj + bb2 - 1;
      if((unsigned)Y < 64u && (unsigned)Xc < 64u)
        v = fp[c2 * (HF*HF) + (Y << 8) + (Xc << 1)];
      v *= 1024.0f;
    }
    _Float16 h0 = (_Float16)v;
    h0v[i] = h0;
    h1v[i] = (_Float16)(v - (float)h0);
  }
  size_t off = (size_t)n * KCH + kb;
  if(isW){
    *(half8*)(Wps + off)         = h0v;
    *(half8*)(Wps + PLANE + off) = h1v;
  } else {
    *(half8*)(Xps + off)         = h0v;
    *(half8*)(Xps + PLANE + off) = h1v;
  }
}

// ---- fp16x2 MFMA GEMM, merged 3-phase schedule (r21 proven). 3 split
// terms w0x0 + w0x1 + w1x0, virtual K = 1728 -> 27 BK=64 K-tiles. ----
#define CLUSTER(G,H,BR)                                                          \
  __builtin_amdgcn_s_setprio(1);                                                 \
  _Pragma("unroll")                                                              \
  for(int mf = 0; mf < 4; ++mf)                                                  \
    _Pragma("unroll")                                                            \
    for(int nf = 0; nf < 2; ++nf)                                                \
      _Pragma("unroll")                                                          \
      for(int ks = 0; ks < 2; ++ks)                                              \
        acc[G][mf][H][nf] = __builtin_amdgcn_mfma_f32_16x16x32_f16(              \
            Ar[mf][ks], BR[nf][ks], acc[G][mf][H][nf], 0, 0, 0);                 \
  __builtin_amdgcn_s_setprio(0);

__global__ __launch_bounds__(512, 2) void k_gemm(const _Float16* __restrict__ Wp,
                                                 const _Float16* __restrict__ Xp,
                                                 float* __restrict__ A){
  __shared__ char smem[131072];   // 2 bufs x [Ah0 16K | Ah1 16K | Bh0 16K | Bh1 16K]
  const int tid  = threadIdx.x;
  const int lane = tid & 63, wv = tid >> 6;
  const int wr = wv >> 2, wc = wv & 3;
  const int samp = blockIdx.x >> 8;
  const int bid  = blockIdx.x & 255;
  const _Float16* Wps = Wp + (size_t)samp * (2*PLANE);
  const _Float16* Xps = Xp + (size_t)samp * (2*PLANE);
  float* As = A + (size_t)samp * NS * NS;
  const int xcd = bid & 7, slot = bid >> 3;
  const int bx = ((xcd & 3) << 2) | (slot & 3);
  const int by = ((xcd >> 2) << 3) | (slot >> 2);
  const int bn = by << 8, bs = bx << 8;

  f32x4 acc[2][4][2][2];
  #pragma unroll
  for(int g = 0; g < 2; ++g)
    #pragma unroll
    for(int mf = 0; mf < 4; ++mf)
      #pragma unroll
      for(int h = 0; h < 2; ++h)
        #pragma unroll
        for(int nf = 0; nf < 2; ++nf) acc[g][mf][h][nf] = (f32x4){0.f,0.f,0.f,0.f};

  const int srow = tid >> 3;                        // 0..63
  const int sq8  = ((tid & 7) ^ (srow & 7)) << 3;   // logical k-chunk * 8 elems
  const int ldso = tid << 4;

  auto stage = [&](int bufB, int t, int half){   // half: 0=Ah0 1=Bh0 2=Bh1 3=Ah1
    int term = t / 9;                            // 0:w0x0 1:w0x1 2:w1x0
    int k0 = (t - term * 9) << 6;
    const _Float16* pl;
    int rowbase, ldsbase;
    if(half == 0 || half == 3){
      pl = Wps + (size_t)(term >> 1) * PLANE;
      int g = (half == 3);
      rowbase = bn + (g << 7);
      ldsbase = bufB + (g << 14);
    } else {
      pl = Xps + (size_t)(term & 1) * PLANE;
      int h = (half == 2);
      rowbase = bs + (h << 7);
      ldsbase = bufB + 32768 + (h << 14);
    }
    const _Float16* src = pl + (size_t)(rowbase + srow) * KCH + k0 + sq8;
    gload16(src,            smem + ldsbase + ldso);
    gload16(src + 64*KCH,   smem + ldsbase + 8192 + ldso);
  };

  const int rA  = ((wr << 6) + (lane & 15)) << 7;
  const int rB  = ((wc << 5) + (lane & 15)) << 7;
  const int co0 = (((lane >> 4) ^ (lane & 7)) << 4);

  half8 Ar[4][2], B0r[2][2], B1r[2][2];
  auto readA = [&](int bufB, int g){
    const char* base = smem + bufB + (g << 14) + rA + co0;
    #pragma unroll
    for(int mf = 0; mf < 4; ++mf){
      Ar[mf][0] = *(const half8*)(base + (mf << 11));
      Ar[mf][1] = *(const half8*)(base + (mf << 11) + ((64 ^ co0) - co0)); // byte ^64
    }
  };
  auto readB = [&](int bufB, int h, half8 (*Br)[2]){
    const char* base = smem + bufB + 32768 + (h << 14) + rB + co0;
    #pragma unroll
    for(int nf = 0; nf < 2; ++nf){
      Br[nf][0] = *(const half8*)(base + (nf << 11));
      Br[nf][1] = *(const half8*)(base + (nf << 11) + ((64 ^ co0) - co0));
    }
  };

  stage(0, 0, 0); stage(0, 0, 1); stage(0, 0, 2); stage(0, 0, 3);

  for(int t = 0; t < 27; ++t){
    const int bufB  = (t & 1) << 16;
    const int nbufB = bufB ^ 65536;
    const bool more = (t < 26);
    // ---- P1: needs Ah0 + Bh0 of t ----
    if(more){ stage(nbufB, t+1, 0); asm volatile("s_waitcnt vmcnt(6)" ::: "memory"); }
    else    {                       asm volatile("s_waitcnt vmcnt(4)" ::: "memory"); }
    __builtin_amdgcn_s_barrier(); asm volatile("" ::: "memory");
    readA(bufB, 0); readB(bufB, 0, B0r);
    CLUSTER(0,0,B0r)
    asm volatile("" ::: "memory"); __builtin_amdgcn_s_barrier(); asm volatile("" ::: "memory");
    // ---- P2: needs Bh1 of t ----
    if(more){ stage(nbufB, t+1, 1); stage(nbufB, t+1, 2);
              asm volatile("s_waitcnt vmcnt(8)" ::: "memory"); }
    else    { asm volatile("s_waitcnt vmcnt(2)" ::: "memory"); }
    __builtin_amdgcn_s_barrier(); asm volatile("" ::: "memory");
    readB(bufB, 1, B1r);
    CLUSTER(0,1,B1r)
    asm volatile("" ::: "memory"); __builtin_amdgcn_s_barrier(); asm volatile("" ::: "memory");
    // ---- P3 (merged): needs Ah1 of t; 32 MFMA ----
    if(more){ stage(nbufB, t+1, 3); asm volatile("s_waitcnt vmcnt(8)" ::: "memory"); }
    else    {                       asm volatile("s_waitcnt vmcnt(0)" ::: "memory"); }
    __builtin_amdgcn_s_barrier(); asm volatile("" ::: "memory");
    readA(bufB, 1);
    CLUSTER(1,1,B1r)
    CLUSTER(1,0,B0r)
    asm volatile("" ::: "memory"); __builtin_amdgcn_s_barrier(); asm volatile("" ::: "memory");
  }

  // C/D mapping (m89-verified): col = lane&15, row = (lane>>4)*4 + reg
  #pragma unroll
  for(int g = 0; g < 2; ++g)
    #pragma unroll
    for(int mf = 0; mf < 4; ++mf){
      int row0 = bn + (g << 7) + (wr << 6) + (mf << 4) + ((lane >> 4) << 2);
      #pragma unroll
      for(int h = 0; h < 2; ++h)
        #pragma unroll
        for(int nf = 0; nf < 2; ++nf){
          int col = bs + (h << 7) + (wc << 5) + (nf << 4) + (lane & 15);
          #pragma unroll
          for(int r = 0; r < 4; ++r)
            As[((size_t)(row0 + r) << 12) + col] = acc[g][mf][h][nf][r];
        }
    }
}

// ---- FUSE pass 1: flat diagonal 3-tap blur. Batched-capable: samp = bid>>12 ----
__global__ __launch_bounds__(256) void k_f1(const float* __restrict__ A,
                                            float* __restrict__ B){
  const int samp = blockIdx.x >> 12;
  const int sbid = blockIdx.x & 4095;
  const int n = ((sbid & 7) << 9) | (sbid >> 3);
  const int tid = threadIdx.x;
  const float* As = A + (size_t)samp * NS * NS;
  float* Bs = B + (size_t)samp * NS * NS;
  const float* r0 = As + ((size_t)n << 12);
  const float* rm = r0 - 4096;
  const float* rp = r0 + 4096;
  const bool vm = (n >= 1), vp = (n <= 4094);
  float* Bw = Bs + ((size_t)n << 12);
  const float4 z4 = {0.f, 0.f, 0.f, 0.f};
  #pragma unroll
  for(int it = 0; it < 4; ++it){
    int cb = ((it << 8) + tid) << 2;      // 0..4092, step 4
    float4 f0 = *(const float4*)(r0 + cb);
    float4 fm = vm ? *(const float4*)(rm + cb) : z4;
    float4 fp = vp ? *(const float4*)(rp + cb) : z4;
    float sm = (vm && cb > 0)    ? rm[cb - 1] : 0.f;
    float sp = (vp && cb < 4092) ? rp[cb + 4] : 0.f;
    float4 o;
    {
      float t0 = sm;           t0 += f0.x; t0 += fp.y;               o.x = t0;
      float t1 = fm.x;         t1 += f0.y; t1 += fp.z;               o.y = t1;
      float t2 = fm.y;         t2 += f0.z; t2 += fp.w;               o.z = t2;
      float t3 = fm.z;         t3 += f0.w; t3 += sp;                 o.w = t3;
    }
    *(float4*)(Bw + cb) = o;
  }
}

// ---- FUSE pass 2 + softmax/argmax/candidates + offsets, tn-major XCD order,
// wave-butterfly reductions (3 barriers). Batched-capable: samp = bid>>12. ----
__global__ __launch_bounds__(256) void k_f2(const float* __restrict__ B,
                                            const float* __restrict__ mm,
                                            int* __restrict__ cnt, int* __restrict__ cand_s,
                                            float* __restrict__ cand_w,
                                            float* __restrict__ out_off){
  const int samp = blockIdx.x >> 12;
  const int sbid = blockIdx.x & 4095;
  const int tn = ((sbid & 7) << 9) | (sbid >> 3);   // tn-major order
  const int n  = Tsw(tn);
  const int tid = threadIdx.x;
  const float* Bs = B + (size_t)samp * NS * NS;
  int* cnts = cnt + samp * NS;
  int* cand_ss = cand_s + samp * NS * 16;
  float* cand_ws = cand_w + samp * NS * 16;
  float* oo = out_off + samp * 2 * NS;
  __shared__ float fw[4];
  __shared__ int   iw[4];
  __shared__ int   s_cnt, s_cs[16];
  __shared__ float s_ce[16];

  const bool v2m = (tn >= 1), v2p = (tn <= 4094);
  const float* Rm = Bs + ((size_t)(v2m ? Tsw(tn - 1) : 0) << 12);
  const float* R0 = Bs + ((size_t)n << 12);
  const float* Rp = Bs + ((size_t)(v2p ? Tsw(tn + 1) : 0) << 12);

  const int wv = tid >> 6, ln = tid & 63;

  float z[16];
  #pragma unroll
  for(int r = 0; r < 16; ++r){
    int s = tid + (r << 8);
    int a = (r << 2) + wv;
    float tm = 0.f;
    if(v2m){
      if(a >= 1)            tm = Rm[s - 64];
      else if(ln >= 1)      tm = Rm[4031 + ln];
    }
    float t = tm;
    t += R0[s];
    float tp = 0.f;
    if(v2p){
      if(a <= 62)           tp = Rp[s + 64];
      else if(ln <= 62)     tp = Rp[ln + 1];
    }
    t += tp;
    z[r] = t;
  }

  float mmv[16];
  float lm = -3.4e38f;
  #pragma unroll
  for(int r = 0; r < 16; ++r){
    mmv[r] = mm[tid + (r << 8)];
    z[r] = z[r] * mmv[r] * 10.0f;
    lm = fmaxf(lm, z[r]);
  }
  #pragma unroll
  for(int off = 32; off > 0; off >>= 1) lm = fmaxf(lm, __shfl_xor(lm, off));
  if(ln == 0) fw[wv] = lm;
  if(tid == 0) s_cnt = 0;
  __syncthreads();
  const float mx = fmaxf(fmaxf(fw[0], fw[1]), fmaxf(fw[2], fw[3]));

  float sum = 0.f, best = -1.0f; int bidx = 0;
  #pragma unroll
  for(int r = 0; r < 16; ++r){
    float d = z[r] - mx;
    float e = 0.f;
    if(__any(d > -20.0f)) e = expf(d);
    sum += e;
    float pe = e * mmv[r];
    int s = tid + (r << 8);
    if(pe > best){ best = pe; bidx = s; }
    if(pe > 1e-6f){
      int sl = atomicAdd(&s_cnt, 1);
      if(sl < 16){ s_cs[sl] = s; s_ce[sl] = pe; }
    }
  }
  #pragma unroll
  for(int off = 32; off > 0; off >>= 1) sum += __shfl_xor(sum, off);
  if(ln == 0) fw[wv] = sum;
  __syncthreads();
  const float s_sum = fw[0] + fw[1] + fw[2] + fw[3];
  __syncthreads();

  #pragma unroll
  for(int off = 32; off > 0; off >>= 1){
    float ov = __shfl_xor(best, off);
    int   oi = __shfl_xor(bidx, off);
    if(ov > best || (ov == best && oi < bidx)){ best = ov; bidx = oi; }
  }
  if(ln == 0){ fw[wv] = best; iw[wv] = bidx; }
  __syncthreads();

  if(tid == 0){
    float vA = fw[0]; int sA = iw[0];
    #pragma unroll
    for(int q = 1; q < 4; ++q){
      float v2 = fw[q]; int j2 = iw[q];
      if(v2 > vA || (v2 == vA && j2 < sA)){ vA = v2; sA = j2; }
    }
    int sBest = (vA > 0.0f) ? sA : 0;
    int c = min(s_cnt, 16);
    if(vA > 0.0f){
      bool found = false;
      for(int q = 0; q < c; ++q) if(s_cs[q] == sA) found = true;
      if(!found){ if(c < 16){ s_cs[c] = sA; s_ce[c] = vA; ++c; } else { s_cs[0] = sA; s_ce[0] = vA; } }
    }
    cnts[n] = c;
    float inv = 1.0f / s_sum;
    for(int q = 0; q < c; ++q){ cand_ss[n*16+q] = s_cs[q]; cand_ws[n*16+q] = s_ce[q] * inv; }
    oo[n]      = (float)((sBest >> 7)  - (n >> 6));
    oo[NS + n] = (float)((sBest & 127) - (n & 63));
  }
}

// ---- y output, co-fast: block = 16 px x 64 co; tap data wave-uniform.
// Batched-capable: samp = bid>>10. ----
__global__ __launch_bounds__(256) void k_y(const float* __restrict__ b,
                    const int* __restrict__ cnt, const int* __restrict__ cand_s,
                    const float* __restrict__ cand_w, float* __restrict__ outy){
  __shared__ float lv[16 * 65];
  const int samp = blockIdx.x >> 10;
  const int sb  = blockIdx.x & 1023;
  const float* bp = b + (size_t)samp * IMG;
  const int* cnts = cnt + samp * NS;
  const int* cand_ss = cand_s + samp * NS * 16;
  const float* cand_ws = cand_w + samp * NS * 16;
  float* oys = outy + (size_t)samp * IMG;
  const int oy  = sb >> 3;
  const int ox0 = (sb & 7) << 4;
  const int co  = threadIdx.x & 63, pq = threadIdx.x >> 6;
  const int kyp = oy & 1;
  const int xb  = 2 * co - 1;

  #pragma unroll
  for(int rr = 0; rr < 4; ++rr){
    const int px = (pq << 2) + rr;
    const int ox = ox0 + px;
    const int kxp = ox & 1;
    float val = 0.f;
    #pragma unroll
    for(int ia = 0; ia < 2; ++ia){
      int ky = kyp + 2*ia;
      int un = oy + ky - 2;
      if(un < 0 || un > 126) continue;
      int u = un >> 1;
      #pragma unroll
      for(int ib = 0; ib < 2; ++ib){
        int kx = kxp + 2*ib;
        int vn = ox + kx - 2;
        if(vn < 0 || vn > 126) continue;
        int v = vn >> 1;
        int n = (u << 6) | v;
        int c = cnts[n];
        int ky2 = 3 - ky, kx2 = 3 - kx;
        for(int q = 0; q < c; ++q){
          int s = cand_ss[n*16 + q];
          float w = cand_ws[n*16 + q];
          int p = s >> 8, ki = p >> 2, kj = p & 3, ch = (s >> 2) & 63;
          int Y = ((s & 3) << 4) + (ky2 << 2) + kx2;
          int yy = ki + 2*Y - 1;
          int xx = kj + xb;
          if(yy >= 0 && yy < HF && (unsigned)xx < (unsigned)HF)
            val += w * bp[(ch << 14) + (yy << 7) + xx];
        }
      }
    }
    lv[px * 65 + co] = val * 0.25f;
  }
  __syncthreads();
  const int pxw = threadIdx.x & 15;
  const int cw0 = threadIdx.x >> 4;
  #pragma unroll
  for(int it = 0; it < 4; ++it){
    int c2 = cw0 + (it << 4);
    oys[(c2 << 14) + (oy << 7) + ox0 + pxw] = lv[pxw * 65 + c2];
  }
}

extern "C" void kernel_launch(void* const* d_in, const int* in_sizes, int n_in,
                              void* d_out, int out_size, void* d_ws, size_t ws_size,
                              hipStream_t stream){
  const float* f    = (const float*)d_in[0];
  const float* b    = (const float*)d_in[1];
  const float* mask = (const float*)d_in[2];
  float* out = (float*)d_out;
  char* ws = (char*)d_ws;

  // Fully-batched layout: A 128MB | Bf 128MB (aliases dead planes) | small.
  const size_t FULL_WS = 269512704ull;   // ~257 MB
  // Semi-batched (r20 proven): A 128MB | planes / Bf-aliased 67MB | small.
  const size_t SEMI_WS = 201883648ull;

  if(ws_size >= FULL_WS){
    float*    A      = (float*)(ws);                        // 2 x 64 MB
    _Float16* Wp     = (_Float16*)(ws + 134217728ull);      // 2 x 9 MB (dead after gemm)
    _Float16* Xp     = (_Float16*)(ws + 153092096ull);      // 2 x 9 MB
    float*    Bf     = (float*)(ws + 134217728ull);         // 2 x 64 MB, aliases planes
    float*    mmv    = (float*)(ws + 268435456ull);
    int*      cntv   = (int*)  (ws + 268451840ull);         // 2 x 16 KB
    int*      cand_s = (int*)  (ws + 268484608ull);         // 2 x 256 KB
    float*    cand_w = (float*)(ws + 269008896ull);         // 2 x 256 KB

    k_mm<<<16, 256, 0, stream>>>(mask, mmv);
    k_WX<<<4608, 256, 0, stream>>>(f, b, Wp, Xp);
    k_gemm<<<512, 512, 0, stream>>>(Wp, Xp, A);
    k_f1<<<8192, 256, 0, stream>>>(A, Bf);
    k_f2<<<8192, 256, 0, stream>>>(Bf, mmv, cntv, cand_s, cand_w, out + 2*IMG);
    k_y<<<2048, 256, 0, stream>>>(b, cntv, cand_s, cand_w, out);
  } else if(ws_size >= SEMI_WS){
    float*    A      = (float*)(ws);                        // 2 x 64 MB
    _Float16* Wp     = (_Float16*)(ws + 134217728ull);
    _Float16* Xp     = (_Float16*)(ws + 153092096ull);
    float*    Bf     = (float*)(ws + 134217728ull);         // 64 MB, aliases planes
    float*    mmv    = (float*)(ws + 201326592ull);
    int*      cntv   = (int*)  (ws + 201342976ull);
    int*      cand_s = (int*)  (ws + 201359360ull);
    float*    cand_w = (float*)(ws + 201621504ull);

    k_mm<<<16, 256, 0, stream>>>(mask, mmv);
    k_WX<<<4608, 256, 0, stream>>>(f, b, Wp, Xp);
    k_gemm<<<512, 512, 0, stream>>>(Wp, Xp, A);
    for(int s = 0; s < 2; ++s){
      const float* bp = b + (size_t)s * IMG;
      k_f1<<<4096, 256, 0, stream>>>(A + (size_t)s * NS * NS, Bf);
      k_f2<<<4096, 256, 0, stream>>>(Bf, mmv, cntv, cand_s, cand_w,
                                     out + 2*IMG + s*2*NS);
      k_y<<<1024, 256, 0, stream>>>(bp, cntv, cand_s, cand_w,
                                    out + (size_t)s * IMG);
    }
  } else {
    // Last-resort per-sample layout.
    float*     A      = (float*)(ws);                       // 64 MB
    float*     Bf     = (float*)(ws + 67108864ull);         // 64 MB
    _Float16*  Wp     = (_Float16*)(ws + 134217728ull);
    _Float16*  Xp     = (_Float16*)(ws + 143654912ull);
    float*     mmv    = (float*)(ws + 153092096ull);
    int*       cntv   = (int*)  (ws + 153108480ull);
    int*       cand_s = (int*)  (ws + 153124864ull);
    float*     cand_w = (float*)(ws + 153387008ull);

    k_mm<<<16, 256, 0, stream>>>(mask, mmv);
    for(int s = 0; s < 2; ++s){
      const float* fp = f + (size_t)s * IMG;
      const float* bp = b + (size_t)s * IMG;
      k_WX<<<2304, 256, 0, stream>>>(fp, bp, Wp, Xp);
      k_gemm<<<256, 512, 0, stream>>>(Wp, Xp, A);
      k_f1<<<4096, 256, 0, stream>>>(A, Bf);
      k_f2<<<4096, 256, 0, stream>>>(Bf, mmv, cntv, cand_s, cand_w,
                                     out + 2*IMG + s*2*NS);
      k_y<<<1024, 256, 0, stream>>>(bp, cntv, cand_s, cand_w,
                                    out + (size_t)s * IMG);
    }
  }
}

// Round 24
// 294.240 us; speedup vs baseline: 1.0249x; 1.0249x over previous
//
#include <hip/hip_runtime.h>
#include <math.h>

#define NS   4096   // L = 64*64
#define KCH  576    // 64 ch * 3 * 3
#define CH   64
#define HF   128    // full res
#define HD   64     // downsampled res
#define PLANE (NS*KCH)   // elements per fp16 plane
#define IMG  (CH*HF*HF)

typedef __attribute__((ext_vector_type(8))) _Float16 half8;
typedef __attribute__((ext_vector_type(4))) float f32x4;

__device__ __forceinline__ int Tsw(int r){ return ((r & 63) << 6) | (r >> 6); }

typedef __attribute__((address_space(1))) unsigned int gu32;
typedef __attribute__((address_space(3))) unsigned int lu32;
__device__ __forceinline__ void gload16(const void* g, void* l){
  __builtin_amdgcn_global_load_lds((const gu32*)g, (lu32*)l, 16, 0, 0);
}

// ---- mm mask vector (batch 0 of mask only, per reference) ----
__global__ void k_mm(const float* __restrict__ mask, float* __restrict__ mm){
  int n = blockIdx.x * blockDim.x + threadIdx.x;
  if(n >= NS) return;
  float sum = 0.f;
  #pragma unroll
  for(int r9 = 0; r9 < 9; ++r9){
    int idx = n * 9 + r9;
    int p   = idx >> 12;
    int rem = idx & 4095;
    int y = rem >> 6, x = rem & 63;
    int ki = p / 3, kj = p % 3;
    int Y = ki + y - 1, X = kj + x - 1;
    float v = 0.f;
    if(Y >= 0 && Y < HD && X >= 0 && X < HD)
      v = mask[(2*Y) * HF + 2*X];
    sum += v;
  }
  mm[n] = ((sum / 9.0f) == 0.0f) ? 1.0f : 0.0f;
}

// ---- W planes (n-major, scaled by 1e4/1024) and X planes (s-major, scaled by
// 1024), fp16x2: plane0 = rne16(v), plane1 = rne16(v - plane0).
// Batched-capable: samp = e0 / (2*PLANE). ----
__global__ void k_WX(const float* __restrict__ f, const float* __restrict__ b,
                     _Float16* __restrict__ Wp, _Float16* __restrict__ Xp){
  int e0 = blockIdx.x * 256 + threadIdx.x;
  int samp = e0 / (2*PLANE);
  int ew = e0 - samp * (2*PLANE);
  const float* fp = f + (size_t)samp * IMG;
  const float* bp = b + (size_t)samp * IMG;
  _Float16* Wps = Wp + (size_t)samp * (2*PLANE);
  _Float16* Xps = Xp + (size_t)samp * (2*PLANE);
  if(ew < PLANE){                          // W part: e = n*576 + k
    int e = ew;
    int n = e / KCH, k = e - n * KCH;
    int c2 = k / 9, r9 = k - c2 * 9;
    int t = n * 9 + r9;                 // the scrambling: 64 not divisible by 9
    int y = t & 63, ch = (t >> 6) & 63, p = t >> 12;
    int ki = p / 3, kj = p - ki * 3;
    int Y = ki + y - 1, X = kj + c2 - 1;
    float v = 0.f;
    if((unsigned)Y < 64u && (unsigned)X < 64u)
      v = bp[ch * (HF*HF) + (Y << 8) + (X << 1)];
    v *= 9.765625f;                     // 1e4 / 1024, exact
    _Float16 h0 = (_Float16)v;
    _Float16 h1 = (_Float16)(v - (float)h0);
    Wps[e] = h0; Wps[PLANE + e] = h1;
  } else {                                 // X part: e = s*576 + k
    int e = ew - PLANE;
    int s = e / KCH, k = e - s * KCH;
    int c2 = k / 9, r9 = k - c2 * 9, a = r9 / 3, bb = r9 - a * 3;
    int i = s >> 6, j = s & 63;
    int Y = i + a - 1, Xc = j + bb - 1;
    float v = 0.f;
    if((unsigned)Y < 64u && (unsigned)Xc < 64u)
      v = fp[c2 * (HF*HF) + (Y << 8) + (Xc << 1)];
    v *= 1024.0f;
    _Float16 h0 = (_Float16)v;
    _Float16 h1 = (_Float16)(v - (float)h0);
    Xps[e] = h0; Xps[PLANE + e] = h1;
  }
}

// ---- fp16x2 MFMA GEMM, merged 3-phase schedule (r21 proven). 3 split
// terms w0x0 + w0x1 + w1x0, virtual K = 1728 -> 27 BK=64 K-tiles. ----
#define CLUSTER(G,H,BR)                                                          \
  __builtin_amdgcn_s_setprio(1);                                                 \
  _Pragma("unroll")                                                              \
  for(int mf = 0; mf < 4; ++mf)                                                  \
    _Pragma("unroll")                                                            \
    for(int nf = 0; nf < 2; ++nf)                                                \
      _Pragma("unroll")                                                          \
      for(int ks = 0; ks < 2; ++ks)                                              \
        acc[G][mf][H][nf] = __builtin_amdgcn_mfma_f32_16x16x32_f16(              \
            Ar[mf][ks], BR[nf][ks], acc[G][mf][H][nf], 0, 0, 0);                 \
  __builtin_amdgcn_s_setprio(0);

__global__ __launch_bounds__(512, 2) void k_gemm(const _Float16* __restrict__ Wp,
                                                 const _Float16* __restrict__ Xp,
                                                 float* __restrict__ A){
  __shared__ char smem[131072];   // 2 bufs x [Ah0 16K | Ah1 16K | Bh0 16K | Bh1 16K]
  const int tid  = threadIdx.x;
  const int lane = tid & 63, wv = tid >> 6;
  const int wr = wv >> 2, wc = wv & 3;
  const int samp = blockIdx.x >> 8;
  const int bid  = blockIdx.x & 255;
  const _Float16* Wps = Wp + (size_t)samp * (2*PLANE);
  const _Float16* Xps = Xp + (size_t)samp * (2*PLANE);
  float* As = A + (size_t)samp * NS * NS;
  const int xcd = bid & 7, slot = bid >> 3;
  const int bx = ((xcd & 3) << 2) | (slot & 3);
  const int by = ((xcd >> 2) << 3) | (slot >> 2);
  const int bn = by << 8, bs = bx << 8;

  f32x4 acc[2][4][2][2];
  #pragma unroll
  for(int g = 0; g < 2; ++g)
    #pragma unroll
    for(int mf = 0; mf < 4; ++mf)
      #pragma unroll
      for(int h = 0; h < 2; ++h)
        #pragma unroll
        for(int nf = 0; nf < 2; ++nf) acc[g][mf][h][nf] = (f32x4){0.f,0.f,0.f,0.f};

  const int srow = tid >> 3;                        // 0..63
  const int sq8  = ((tid & 7) ^ (srow & 7)) << 3;   // logical k-chunk * 8 elems
  const int ldso = tid << 4;

  auto stage = [&](int bufB, int t, int half){   // half: 0=Ah0 1=Bh0 2=Bh1 3=Ah1
    int term = t / 9;                            // 0:w0x0 1:w0x1 2:w1x0
    int k0 = (t - term * 9) << 6;
    const _Float16* pl;
    int rowbase, ldsbase;
    if(half == 0 || half == 3){
      pl = Wps + (size_t)(term >> 1) * PLANE;
      int g = (half == 3);
      rowbase = bn + (g << 7);
      ldsbase = bufB + (g << 14);
    } else {
      pl = Xps + (size_t)(term & 1) * PLANE;
      int h = (half == 2);
      rowbase = bs + (h << 7);
      ldsbase = bufB + 32768 + (h << 14);
    }
    const _Float16* src = pl + (size_t)(rowbase + srow) * KCH + k0 + sq8;
    gload16(src,            smem + ldsbase + ldso);
    gload16(src + 64*KCH,   smem + ldsbase + 8192 + ldso);
  };

  const int rA  = ((wr << 6) + (lane & 15)) << 7;
  const int rB  = ((wc << 5) + (lane & 15)) << 7;
  const int co0 = (((lane >> 4) ^ (lane & 7)) << 4);

  half8 Ar[4][2], B0r[2][2], B1r[2][2];
  auto readA = [&](int bufB, int g){
    const char* base = smem + bufB + (g << 14) + rA + co0;
    #pragma unroll
    for(int mf = 0; mf < 4; ++mf){
      Ar[mf][0] = *(const half8*)(base + (mf << 11));
      Ar[mf][1] = *(const half8*)(base + (mf << 11) + ((64 ^ co0) - co0)); // byte ^64
    }
  };
  auto readB = [&](int bufB, int h, half8 (*Br)[2]){
    const char* base = smem + bufB + 32768 + (h << 14) + rB + co0;
    #pragma unroll
    for(int nf = 0; nf < 2; ++nf){
      Br[nf][0] = *(const half8*)(base + (nf << 11));
      Br[nf][1] = *(const half8*)(base + (nf << 11) + ((64 ^ co0) - co0));
    }
  };

  stage(0, 0, 0); stage(0, 0, 1); stage(0, 0, 2); stage(0, 0, 3);

  for(int t = 0; t < 27; ++t){
    const int bufB  = (t & 1) << 16;
    const int nbufB = bufB ^ 65536;
    const bool more = (t < 26);
    // ---- P1: needs Ah0 + Bh0 of t ----
    if(more){ stage(nbufB, t+1, 0); asm volatile("s_waitcnt vmcnt(6)" ::: "memory"); }
    else    {                       asm volatile("s_waitcnt vmcnt(4)" ::: "memory"); }
    __builtin_amdgcn_s_barrier(); asm volatile("" ::: "memory");
    readA(bufB, 0); readB(bufB, 0, B0r);
    CLUSTER(0,0,B0r)
    asm volatile("" ::: "memory"); __builtin_amdgcn_s_barrier(); asm volatile("" ::: "memory");
    // ---- P2: needs Bh1 of t ----
    if(more){ stage(nbufB, t+1, 1); stage(nbufB, t+1, 2);
              asm volatile("s_waitcnt vmcnt(8)" ::: "memory"); }
    else    { asm volatile("s_waitcnt vmcnt(2)" ::: "memory"); }
    __builtin_amdgcn_s_barrier(); asm volatile("" ::: "memory");
    readB(bufB, 1, B1r);
    CLUSTER(0,1,B1r)
    asm volatile("" ::: "memory"); __builtin_amdgcn_s_barrier(); asm volatile("" ::: "memory");
    // ---- P3 (merged): needs Ah1 of t; 32 MFMA ----
    if(more){ stage(nbufB, t+1, 3); asm volatile("s_waitcnt vmcnt(8)" ::: "memory"); }
    else    {                       asm volatile("s_waitcnt vmcnt(0)" ::: "memory"); }
    __builtin_amdgcn_s_barrier(); asm volatile("" ::: "memory");
    readA(bufB, 1);
    CLUSTER(1,1,B1r)
    CLUSTER(1,0,B0r)
    asm volatile("" ::: "memory"); __builtin_amdgcn_s_barrier(); asm volatile("" ::: "memory");
  }

  // C/D mapping (m89-verified): col = lane&15, row = (lane>>4)*4 + reg
  #pragma unroll
  for(int g = 0; g < 2; ++g)
    #pragma unroll
    for(int mf = 0; mf < 4; ++mf){
      int row0 = bn + (g << 7) + (wr << 6) + (mf << 4) + ((lane >> 4) << 2);
      #pragma unroll
      for(int h = 0; h < 2; ++h)
        #pragma unroll
        for(int nf = 0; nf < 2; ++nf){
          int col = bs + (h << 7) + (wc << 5) + (nf << 4) + (lane & 15);
          #pragma unroll
          for(int r = 0; r < 4; ++r)
            As[((size_t)(row0 + r) << 12) + col] = acc[g][mf][h][nf][r];
        }
    }
}

// ---- FUSE pass 1: flat diagonal 3-tap blur. Batched-capable: samp = bid>>12 ----
__global__ __launch_bounds__(256) void k_f1(const float* __restrict__ A,
                                            float* __restrict__ B){
  const int samp = blockIdx.x >> 12;
  const int sbid = blockIdx.x & 4095;
  const int n = ((sbid & 7) << 9) | (sbid >> 3);
  const int tid = threadIdx.x;
  const float* As = A + (size_t)samp * NS * NS;
  float* Bs = B + (size_t)samp * NS * NS;
  const float* r0 = As + ((size_t)n << 12);
  const float* rm = r0 - 4096;
  const float* rp = r0 + 4096;
  const bool vm = (n >= 1), vp = (n <= 4094);
  float* Bw = Bs + ((size_t)n << 12);
  const float4 z4 = {0.f, 0.f, 0.f, 0.f};
  #pragma unroll
  for(int it = 0; it < 4; ++it){
    int cb = ((it << 8) + tid) << 2;      // 0..4092, step 4
    float4 f0 = *(const float4*)(r0 + cb);
    float4 fm = vm ? *(const float4*)(rm + cb) : z4;
    float4 fp = vp ? *(const float4*)(rp + cb) : z4;
    float sm = (vm && cb > 0)    ? rm[cb - 1] : 0.f;
    float sp = (vp && cb < 4092) ? rp[cb + 4] : 0.f;
    float4 o;
    {
      float t0 = sm;           t0 += f0.x; t0 += fp.y;               o.x = t0;
      float t1 = fm.x;         t1 += f0.y; t1 += fp.z;               o.y = t1;
      float t2 = fm.y;         t2 += f0.z; t2 += fp.w;               o.z = t2;
      float t3 = fm.z;         t3 += f0.w; t3 += sp;                 o.w = t3;
    }
    *(float4*)(Bw + cb) = o;
  }
}

// ---- FUSE pass 2 + softmax/argmax/candidates + offsets, tn-major XCD order,
// wave-butterfly reductions (3 barriers). Batched-capable: samp = bid>>12. ----
__global__ __launch_bounds__(256) void k_f2(const float* __restrict__ B,
                                            const float* __restrict__ mm,
                                            int* __restrict__ cnt, int* __restrict__ cand_s,
                                            float* __restrict__ cand_w,
                                            float* __restrict__ out_off){
  const int samp = blockIdx.x >> 12;
  const int sbid = blockIdx.x & 4095;
  const int tn = ((sbid & 7) << 9) | (sbid >> 3);   // tn-major order
  const int n  = Tsw(tn);
  const int tid = threadIdx.x;
  const float* Bs = B + (size_t)samp * NS * NS;
  int* cnts = cnt + samp * NS;
  int* cand_ss = cand_s + samp * NS * 16;
  float* cand_ws = cand_w + samp * NS * 16;
  float* oo = out_off + samp * 2 * NS;
  __shared__ float fw[4];
  __shared__ int   iw[4];
  __shared__ int   s_cnt, s_cs[16];
  __shared__ float s_ce[16];

  const bool v2m = (tn >= 1), v2p = (tn <= 4094);
  const float* Rm = Bs + ((size_t)(v2m ? Tsw(tn - 1) : 0) << 12);
  const float* R0 = Bs + ((size_t)n << 12);
  const float* Rp = Bs + ((size_t)(v2p ? Tsw(tn + 1) : 0) << 12);

  const int wv = tid >> 6, ln = tid & 63;

  float z[16];
  #pragma unroll
  for(int r = 0; r < 16; ++r){
    int s = tid + (r << 8);
    int a = (r << 2) + wv;
    float tm = 0.f;
    if(v2m){
      if(a >= 1)            tm = Rm[s - 64];
      else if(ln >= 1)      tm = Rm[4031 + ln];
    }
    float t = tm;
    t += R0[s];
    float tp = 0.f;
    if(v2p){
      if(a <= 62)           tp = Rp[s + 64];
      else if(ln <= 62)     tp = Rp[ln + 1];
    }
    t += tp;
    z[r] = t;
  }

  float mmv[16];
  float lm = -3.4e38f;
  #pragma unroll
  for(int r = 0; r < 16; ++r){
    mmv[r] = mm[tid + (r << 8)];
    z[r] = z[r] * mmv[r] * 10.0f;
    lm = fmaxf(lm, z[r]);
  }
  #pragma unroll
  for(int off = 32; off > 0; off >>= 1) lm = fmaxf(lm, __shfl_xor(lm, off));
  if(ln == 0) fw[wv] = lm;
  if(tid == 0) s_cnt = 0;
  __syncthreads();
  const float mx = fmaxf(fmaxf(fw[0], fw[1]), fmaxf(fw[2], fw[3]));

  float sum = 0.f, best = -1.0f; int bidx = 0;
  #pragma unroll
  for(int r = 0; r < 16; ++r){
    float d = z[r] - mx;
    float e = 0.f;
    if(__any(d > -20.0f)) e = expf(d);
    sum += e;
    float pe = e * mmv[r];
    int s = tid + (r << 8);
    if(pe > best){ best = pe; bidx = s; }
    if(pe > 1e-6f){
      int sl = atomicAdd(&s_cnt, 1);
      if(sl < 16){ s_cs[sl] = s; s_ce[sl] = pe; }
    }
  }
  #pragma unroll
  for(int off = 32; off > 0; off >>= 1) sum += __shfl_xor(sum, off);
  if(ln == 0) fw[wv] = sum;
  __syncthreads();
  const float s_sum = fw[0] + fw[1] + fw[2] + fw[3];
  __syncthreads();

  #pragma unroll
  for(int off = 32; off > 0; off >>= 1){
    float ov = __shfl_xor(best, off);
    int   oi = __shfl_xor(bidx, off);
    if(ov > best || (ov == best && oi < bidx)){ best = ov; bidx = oi; }
  }
  if(ln == 0){ fw[wv] = best; iw[wv] = bidx; }
  __syncthreads();

  if(tid == 0){
    float vA = fw[0]; int sA = iw[0];
    #pragma unroll
    for(int q = 1; q < 4; ++q){
      float v2 = fw[q]; int j2 = iw[q];
      if(v2 > vA || (v2 == vA && j2 < sA)){ vA = v2; sA = j2; }
    }
    int sBest = (vA > 0.0f) ? sA : 0;
    int c = min(s_cnt, 16);
    if(vA > 0.0f){
      bool found = false;
      for(int q = 0; q < c; ++q) if(s_cs[q] == sA) found = true;
      if(!found){ if(c < 16){ s_cs[c] = sA; s_ce[c] = vA; ++c; } else { s_cs[0] = sA; s_ce[0] = vA; } }
    }
    cnts[n] = c;
    float inv = 1.0f / s_sum;
    for(int q = 0; q < c; ++q){ cand_ss[n*16+q] = s_cs[q]; cand_ws[n*16+q] = s_ce[q] * inv; }
    oo[n]      = (float)((sBest >> 7)  - (n >> 6));
    oo[NS + n] = (float)((sBest & 127) - (n & 63));
  }
}

// ---- y output, co-fast: block = 16 px x 64 co; tap data wave-uniform.
// Batched-capable: samp = bid>>10. ----
__global__ __launch_bounds__(256) void k_y(const float* __restrict__ b,
                    const int* __restrict__ cnt, const int* __restrict__ cand_s,
                    const float* __restrict__ cand_w, float* __restrict__ outy){
  __shared__ float lv[16 * 65];
  const int samp = blockIdx.x >> 10;
  const int sb  = blockIdx.x & 1023;
  const float* bp = b + (size_t)samp * IMG;
  const int* cnts = cnt + samp * NS;
  const int* cand_ss = cand_s + samp * NS * 16;
  const float* cand_ws = cand_w + samp * NS * 16;
  float* oys = outy + (size_t)samp * IMG;
  const int oy  = sb >> 3;
  const int ox0 = (sb & 7) << 4;
  const int co  = threadIdx.x & 63, pq = threadIdx.x >> 6;
  const int kyp = oy & 1;
  const int xb  = 2 * co - 1;

  #pragma unroll
  for(int rr = 0; rr < 4; ++rr){
    const int px = (pq << 2) + rr;
    const int ox = ox0 + px;
    const int kxp = ox & 1;
    float val = 0.f;
    #pragma unroll
    for(int ia = 0; ia < 2; ++ia){
      int ky = kyp + 2*ia;
      int un = oy + ky - 2;
      if(un < 0 || un > 126) continue;
      int u = un >> 1;
      #pragma unroll
      for(int ib = 0; ib < 2; ++ib){
        int kx = kxp + 2*ib;
        int vn = ox + kx - 2;
        if(vn < 0 || vn > 126) continue;
        int v = vn >> 1;
        int n = (u << 6) | v;
        int c = cnts[n];
        int ky2 = 3 - ky, kx2 = 3 - kx;
        for(int q = 0; q < c; ++q){
          int s = cand_ss[n*16 + q];
          float w = cand_ws[n*16 + q];
          int p = s >> 8, ki = p >> 2, kj = p & 3, ch = (s >> 2) & 63;
          int Y = ((s & 3) << 4) + (ky2 << 2) + kx2;
          int yy = ki + 2*Y - 1;
          int xx = kj + xb;
          if(yy >= 0 && yy < HF && (unsigned)xx < (unsigned)HF)
            val += w * bp[(ch << 14) + (yy << 7) + xx];
        }
      }
    }
    lv[px * 65 + co] = val * 0.25f;
  }
  __syncthreads();
  const int pxw = threadIdx.x & 15;
  const int cw0 = threadIdx.x >> 4;
  #pragma unroll
  for(int it = 0; it < 4; ++it){
    int c2 = cw0 + (it << 4);
    oys[(c2 << 14) + (oy << 7) + ox0 + pxw] = lv[pxw * 65 + c2];
  }
}

extern "C" void kernel_launch(void* const* d_in, const int* in_sizes, int n_in,
                              void* d_out, int out_size, void* d_ws, size_t ws_size,
                              hipStream_t stream){
  const float* f    = (const float*)d_in[0];
  const float* b    = (const float*)d_in[1];
  const float* mask = (const float*)d_in[2];
  float* out = (float*)d_out;
  char* ws = (char*)d_ws;

  // Fully-batched layout: A 128MB | Bf 128MB (aliases dead planes) | small.
  const size_t FULL_WS = 269512704ull;   // ~257 MB
  // Semi-batched (r20 proven): A 128MB | planes / Bf-aliased 67MB | small.
  const size_t SEMI_WS = 201883648ull;

  if(ws_size >= FULL_WS){
    float*    A      = (float*)(ws);                        // 2 x 64 MB
    _Float16* Wp     = (_Float16*)(ws + 134217728ull);      // 2 x 9 MB (dead after gemm)
    _Float16* Xp     = (_Float16*)(ws + 153092096ull);      // 2 x 9 MB
    float*    Bf     = (float*)(ws + 134217728ull);         // 2 x 64 MB, aliases planes
    float*    mmv    = (float*)(ws + 268435456ull);
    int*      cntv   = (int*)  (ws + 268451840ull);         // 2 x 16 KB
    int*      cand_s = (int*)  (ws + 268484608ull);         // 2 x 256 KB
    float*    cand_w = (float*)(ws + 269008896ull);         // 2 x 256 KB

    k_mm<<<16, 256, 0, stream>>>(mask, mmv);
    k_WX<<<(4*PLANE)/256, 256, 0, stream>>>(f, b, Wp, Xp);
    k_gemm<<<512, 512, 0, stream>>>(Wp, Xp, A);
    k_f1<<<8192, 256, 0, stream>>>(A, Bf);
    k_f2<<<8192, 256, 0, stream>>>(Bf, mmv, cntv, cand_s, cand_w, out + 2*IMG);
    k_y<<<2048, 256, 0, stream>>>(b, cntv, cand_s, cand_w, out);
  } else if(ws_size >= SEMI_WS){
    float*    A      = (float*)(ws);                        // 2 x 64 MB
    _Float16* Wp     = (_Float16*)(ws + 134217728ull);
    _Float16* Xp     = (_Float16*)(ws + 153092096ull);
    float*    Bf     = (float*)(ws + 134217728ull);         // 64 MB, aliases planes
    float*    mmv    = (float*)(ws + 201326592ull);
    int*      cntv   = (int*)  (ws + 201342976ull);
    int*      cand_s = (int*)  (ws + 201359360ull);
    float*    cand_w = (float*)(ws + 201621504ull);

    k_mm<<<16, 256, 0, stream>>>(mask, mmv);
    k_WX<<<(4*PLANE)/256, 256, 0, stream>>>(f, b, Wp, Xp);
    k_gemm<<<512, 512, 0, stream>>>(Wp, Xp, A);
    for(int s = 0; s < 2; ++s){
      const float* bp = b + (size_t)s * IMG;
      k_f1<<<4096, 256, 0, stream>>>(A + (size_t)s * NS * NS, Bf);
      k_f2<<<4096, 256, 0, stream>>>(Bf, mmv, cntv, cand_s, cand_w,
                                     out + 2*IMG + s*2*NS);
      k_y<<<1024, 256, 0, stream>>>(bp, cntv, cand_s, cand_w,
                                    out + (size_t)s * IMG);
    }
  } else {
    // Last-resort per-sample layout.
    float*     A      = (float*)(ws);                       // 64 MB
    float*     Bf     = (float*)(ws + 67108864ull);         // 64 MB
    _Float16*  Wp     = (_Float16*)(ws + 134217728ull);
    _Float16*  Xp     = (_Float16*)(ws + 143654912ull);
    float*     mmv    = (float*)(ws + 153092096ull);
    int*       cntv   = (int*)  (ws + 153108480ull);
    int*       cand_s = (int*)  (ws + 153124864ull);
    float*     cand_w = (float*)(ws + 153387008ull);

    k_mm<<<16, 256, 0, stream>>>(mask, mmv);
    for(int s = 0; s < 2; ++s){
      const float* fp = f + (size_t)s * IMG;
      const float* bp = b + (size_t)s * IMG;
      k_WX<<<(2*PLANE)/256, 256, 0, stream>>>(fp, bp, Wp, Xp);
      k_gemm<<<256, 512, 0, stream>>>(Wp, Xp, A);
      k_f1<<<4096, 256, 0, stream>>>(A, Bf);
      k_f2<<<4096, 256, 0, stream>>>(Bf, mmv, cntv, cand_s, cand_w,
                                     out + 2*IMG + s*2*NS);
      k_y<<<1024, 256, 0, stream>>>(bp, cntv, cand_s, cand_w,
                                    out + (size_t)s * IMG);
    }
  }
}